// Round 12
// baseline (1027.404 us; speedup 1.0000x reference)
//
#include <hip/hip_runtime.h>
#include <hip/hip_bf16.h>

// ---------------------------------------------------------------------------
// Model2: 5x 4-D conv (+ReLU) -> FC(3840->100)+ReLU -> FC(100->1)+sigmoid
// v12: BARRIER-FREE all-register conv. No LDS, no __syncthreads (whose
// implicit s_waitcnt vmcnt(0) drained the prefetch queue every chunk in
// v5-v11 and pinned MfmaUtil at ~36%). B-fragments read directly from L2
// (wf reused by all blocks -> hot); distance-1 register prefetch of A (6
// loads) + B (4 loads) for group g+1 issued before group g's 12-MFMA burst;
// counted vmcnt keeps 10 loads in flight across group boundaries forever.
// ---------------------------------------------------------------------------

#define BATCH 256
typedef unsigned int u32;
typedef float    f32x4  __attribute__((ext_vector_type(4)));
typedef float    f32x16 __attribute__((ext_vector_type(16)));
typedef _Float16 f16x8  __attribute__((ext_vector_type(8)));

struct __attribute__((packed, aligned(4))) f16x8w { f16x8 v; };  // 4B-aligned 16B load

// --------------------------- fp32 -> f16 convert ---------------------------
__global__ void cvt_f32_f16(const float* __restrict__ in, _Float16* __restrict__ o, int n8) {
    int i = blockIdx.x * blockDim.x + threadIdx.x;
    if (i >= n8) return;
    const f32x4* p = (const f32x4*)(in + (size_t)i * 8);
    f32x4 a = p[0], b = p[1];
    f16x8 v;
    #pragma unroll
    for (int j = 0; j < 4; ++j) { v[j] = (_Float16)a[j]; v[4 + j] = (_Float16)b[j]; }
    *(f16x8*)(o + (size_t)i * 8) = v;
}

// --------------------------- weight prepack (v5 order) ---------------------
// st = ((ci*KS + k2)*2 + k3p)*KS + k1.  Within a step: k_local = g*8 + j,
// k3 = k3p*2 + g, k4' = j.  col = lane&31 = oc*S + s.
template<int COUT, int CIN, int KS, int S>
__global__ void prepack_v5(const float* __restrict__ w, _Float16* __restrict__ wf) {
    constexpr int STEPS = CIN * KS * 2 * KS;
    constexpr int TOT = STEPS * 512;
    int idx = blockIdx.x * 256 + threadIdx.x;
    if (idx >= TOT) return;
    int j    = idx & 7;
    int lane = (idx >> 3) & 63;
    int st   = idx >> 9;
    int k1 = st % KS;
    int r1 = st / KS;
    int k3p = r1 & 1;
    int r2  = r1 >> 1;
    int k2 = r2 % KS;
    int ci = r2 / KS;
    int gg = lane >> 5, col = lane & 31;
    int oc = col / S, s = col % S;
    int k3 = k3p * 2 + gg;
    int k4 = j - s;
    float v = 0.0f;
    if (oc < COUT && k3 < KS && k4 >= 0 && k4 < KS)
        v = w[((((oc * CIN + ci) * KS + k1) * KS + k2) * KS + k3) * KS + k4];
    wf[idx] = (_Float16)v;
}

// --------------------------- conv kernel (v12) -----------------------------
// <..., T, UB, MINW>: UB = inner unroll (even, divides GROUPS).
template<int CIN, int COUT, int KS, int DIN, int DP, int S, int OP, int T,
         int UB, int MINW>
__launch_bounds__(256, MINW)
__global__ void conv4d_v12(const _Float16* __restrict__ x,
                           const _Float16* __restrict__ wf,
                           const float* __restrict__ bias,
                           _Float16* __restrict__ out) {
    constexpr int DOUT = DIN - KS + 1;
    constexpr int NB   = (DOUT + S - 1) / S;
    constexpr int PCOL = DOUT * DOUT * NB;         // (d2,d3,u) rows per (b,d1)
    constexpr int NTC  = (PCOL + 31) / 32;
    constexpr int NG   = DOUT / T;                 // d1 groups
    static_assert(DOUT % T == 0, "T must divide DOUT");
    constexpr int XD2 = DIN * DP;
    constexpr int XD1 = DIN * XD2;
    constexpr int XCI = DIN * XD1;
    constexpr int GROUPS = CIN * KS * 2;
    static_assert(GROUPS % UB == 0, "UB must divide GROUPS");
    static_assert(UB % 2 == 0, "UB even so parity gi&1 is static");
    constexpr int NOUTER = GROUPS / UB;
    constexpr int AJ = T + KS - 1;                 // A rows per group window
    constexpr u32 NW   = (u32)BATCH * NG * NTC;
    constexpr u32 POUT = (u32)DOUT * DOUT * DOUT * OP;

    const int tid = threadIdx.x;
    u32 wid = blockIdx.x * 4u + (u32)(tid >> 6);
    if (wid >= NW) wid = NW - 1u;
    const int ln = tid & 63;
    const int g  = ln >> 5;
    const int r  = ln & 31;

    u32 tc = wid % (u32)NTC;  u32 q = wid / (u32)NTC;
    u32 d1g = q % (u32)NG;    u32 b = q / (u32)NG;
    u32 rr = tc * 32u + (u32)r;  if (rr >= (u32)PCOL) rr = (u32)PCOL - 1u;
    u32 u  = rr % (u32)NB;    u32 q2 = rr / (u32)NB;
    u32 d3 = q2 % (u32)DOUT;  u32 d2 = q2 / (u32)DOUT;

    const u32 lanebase2 = (b * (u32)(CIN * XCI) + d1g * (u32)(T * XD1)
                         + d2 * (u32)XD2 + d3 * (u32)DP + (u32)(g * DP)
                         + u * (u32)S) * 2u;
    const char* xc = (const char*)x;
    const f16x8* wfv = (const f16x8*)wf;

    f32x16 acc[T];
    #pragma unroll
    for (int t = 0; t < T; ++t)
        #pragma unroll
        for (int i = 0; i < 16; ++i) acc[t][i] = 0.0f;

    // Double-buffered A window + B fragments, prefetch distance 1.
    f16x8 ar[2][AJ];
    f16x8 bfb[2][KS];
    {   // preload group 0 (ci=0,k2=0,k3p=0 -> goff 0)
        const char* ap0 = xc + lanebase2;
        #pragma unroll
        for (int j = 0; j < AJ; ++j)
            ar[0][j] = ((const f16x8w*)(ap0 + j * (XD1 * 2)))->v;
        #pragma unroll
        for (int k1 = 0; k1 < KS; ++k1)
            bfb[0][k1] = wfv[k1 * 64 + ln];
    }

    #pragma unroll 1
    for (int c = 0; c < NOUTER; ++c) {
        #pragma unroll
        for (int gi = 0; gi < UB; ++gi) {
            const int grp = c * UB + gi;           // runtime (c) + static (gi)
            constexpr int P0 = 0;  (void)P0;
            const int pcur = gi & 1;               // static under unroll
            const int pnxt = (gi + 1) & 1;
            // 1) prefetch group grp+1 (A rows + B fragments)
            if (grp + 1 < GROUPS) {
                int g2  = grp + 1;
                int k3p = g2 & 1;
                int k2  = (g2 >> 1) % KS;
                int ci  = (g2 >> 1) / KS;
                u32 goff = ((u32)ci * (u32)XCI + (u32)k2 * (u32)XD2
                          + (u32)(k3p * 2 * DP)) * 2u;
                const char* ap = xc + lanebase2 + goff;
                #pragma unroll
                for (int j = 0; j < AJ; ++j)
                    ar[pnxt][j] = ((const f16x8w*)(ap + j * (XD1 * 2)))->v;
                #pragma unroll
                for (int k1 = 0; k1 < KS; ++k1)
                    bfb[pnxt][k1] = wfv[(size_t)(g2 * KS + k1) * 64 + ln];
            }
            // 2) 12 MFMAs for current group, purely from registers
            #pragma unroll
            for (int k1 = 0; k1 < KS; ++k1) {
                #pragma unroll
                for (int t = 0; t < T; ++t)
                    acc[t] = __builtin_amdgcn_mfma_f32_32x32x16_f16(
                        ar[pcur][k1 + t], bfb[pcur][k1], acc[t], 0, 0, 0);
            }
        }
    }

    // Epilogue. D: col = lane&31 = oc*S+s, row = (reg&3) + 8*(reg>>2) + 4*g.
    const int oc = r / S, s = r % S;
    if (oc >= COUT) return;
    float bv = bias[oc];
    #pragma unroll
    for (int reg = 0; reg < 16; ++reg) {
        int rowoff = (reg & 3) + 8 * (reg >> 2) + 4 * g;
        u32 rr2 = tc * 32u + (u32)rowoff;
        if (rr2 >= (u32)PCOL) rr2 = (u32)PCOL - 1u;
        u32 uu = rr2 % (u32)NB;  u32 qq = rr2 / (u32)NB;
        u32 dd3 = qq % (u32)DOUT; u32 dd2 = qq / (u32)DOUT;
        u32 d4 = uu * (u32)S + (u32)s;
        if (d4 < (u32)DOUT) {
            u32 obase = (b * (u32)COUT + (u32)oc) * POUT
                      + (dd2 * (u32)DOUT + dd3) * (u32)OP + d4
                      + d1g * (u32)(T * DOUT * DOUT * OP);
            #pragma unroll
            for (int t = 0; t < T; ++t)
                out[obase + (u32)t * (u32)(DOUT * DOUT * OP)]
                    = (_Float16)fmaxf(acc[t][reg] + bv, 0.0f);
        }
    }
}

// --------------------------- FC1 (MFMA 16x16x32) ---------------------------
__global__ void prepack_fc1(const float* __restrict__ w, _Float16* __restrict__ wf) {
    int idx = blockIdx.x * 256 + threadIdx.x;        // 7*120*64*8 = 430080
    if (idx >= 430080) return;
    int j    = idx & 7;
    int lane = (idx >> 3) & 63;
    int t9   = idx >> 9;
    int st   = t9 % 120;
    int ni   = t9 / 120;
    int k    = st * 32 + (lane >> 4) * 8 + j;
    int col  = ni * 16 + (lane & 15);
    wf[idx] = (_Float16)((col < 100) ? w[k * 100 + col] : 0.0f);
}

__launch_bounds__(256)
__global__ void fc1_mfma(const _Float16* __restrict__ h,
                         const _Float16* __restrict__ wfc,
                         const float* __restrict__ bias,
                         float* __restrict__ o) {
    int wv   = blockIdx.x * 4 + (threadIdx.x >> 6);   // 0..111
    int lane = threadIdx.x & 63;
    int r = lane & 15, g = lane >> 4;
    int mi = wv / 7, ni = wv % 7;
    const f16x8* A  = (const f16x8*)(h + (size_t)(mi * 16 + r) * 3840);
    const f16x8* Bv = (const f16x8*)wfc;
    f32x4 acc = {0.f, 0.f, 0.f, 0.f};
    #pragma unroll 4
    for (int st = 0; st < 120; ++st) {
        f16x8 a = A[st * 4 + g];
        f16x8 b = Bv[(ni * 120 + st) * 64 + lane];
        acc = __builtin_amdgcn_mfma_f32_16x16x32_f16(a, b, acc, 0, 0, 0);
    }
    int col = ni * 16 + r;
    if (col < 100) {
        float bv = bias[col];
        #pragma unroll
        for (int i = 0; i < 4; ++i) {
            int row = mi * 16 + g * 4 + i;
            o[row * 100 + col] = fmaxf(acc[i] + bv, 0.0f);
        }
    }
}

// --------------------------- FC2 + sigmoid ---------------------------------
__global__ void fc2_sigmoid(const float* __restrict__ h,
                            const float* __restrict__ w,
                            const float* __restrict__ bias,
                            float* __restrict__ out) {
    int b = blockIdx.x * blockDim.x + threadIdx.x;
    if (b >= BATCH) return;
    const float* hb = h + b * 100;
    float acc = bias[0];
    #pragma unroll
    for (int j = 0; j < 100; ++j)
        acc = fmaf(hb[j], w[j], acc);
    out[b] = 1.0f / (1.0f + expf(-acc));
}

// --------------------------- launch ----------------------------------------
extern "C" void kernel_launch(void* const* d_in, const int* in_sizes, int n_in,
                              void* d_out, int out_size, void* d_ws, size_t ws_size,
                              hipStream_t stream) {
    const float* x    = (const float*)d_in[0];
    const float* w1   = (const float*)d_in[1];
    const float* b1   = (const float*)d_in[2];
    const float* w2   = (const float*)d_in[3];
    const float* b2   = (const float*)d_in[4];
    const float* w3   = (const float*)d_in[5];
    const float* b3   = (const float*)d_in[6];
    const float* w4   = (const float*)d_in[7];
    const float* b4   = (const float*)d_in[8];
    const float* w5   = (const float*)d_in[9];
    const float* b5   = (const float*)d_in[10];
    const float* fc1w = (const float*)d_in[11];
    const float* fc1b = (const float*)d_in[12];
    const float* fc2w = (const float*)d_in[13];
    const float* fc2b = (const float*)d_in[14];
    float* out = (float*)d_out;

    _Float16* W = (_Float16*)d_ws;
    size_t cur = 0;
    auto alloc = [&](size_t n) { _Float16* p = W + cur; cur += (n + 255) & ~(size_t)255; return p; };
    _Float16* x16 = alloc(26873856);            // [256,1,18,18,18,18]
    _Float16* h1  = alloc(41472000);            // [256,3,15,15,15,(16)]
    _Float16* h2  = alloc(47775744);            // [256,9,12,12,12,12]
    _Float16* h3  = alloc(22394880);            // [256,12,9,9,9,(10)]
    _Float16* h4  = alloc(4976640);             // [256,15,6,6,6,6]
    _Float16* h5  = alloc(983040);              // [256,3840] flatten-exact
    _Float16* wf1 = alloc(16384);               // 32 steps * 512
    _Float16* wf2 = alloc(49152);               // 96
    _Float16* wf3 = alloc(147456);              // 288
    _Float16* wf4 = alloc(196608);              // 384
    _Float16* wf5 = alloc(138240);              // 270
    _Float16* wfc = alloc(430080);
    float* fc1out = (float*)alloc(51200 + 256); // [256,100] f32

    cvt_f32_f16<<<13122, 256, 0, stream>>>(x, x16, 3359232);

    prepack_v5<3, 1, 4, 4><<<64,  256, 0, stream>>>(w1, wf1);
    prepack_v5<9, 3, 4, 2><<<192, 256, 0, stream>>>(w2, wf2);
    prepack_v5<12, 9, 4, 2><<<576, 256, 0, stream>>>(w3, wf3);
    prepack_v5<15, 12, 4, 2><<<768, 256, 0, stream>>>(w4, wf4);
    prepack_v5<15, 15, 3, 2><<<540, 256, 0, stream>>>(w5, wf5);
    prepack_fc1<<<1680, 256, 0, stream>>>(fc1w, wfc);

    // convs: <CIN,COUT,KS,DIN,DP,S,OP,T,UB,MINW>, grid = ceil(NW/4)
    // conv1: GROUPS=8,  T=3 -> NG=5, NW=37120; UB=8
    conv4d_v12<1, 3, 4, 18, 18, 4, 16, 3, 8, 3><<<9280, 256, 0, stream>>>(x16, wf1, b1, h1);
    // conv2: GROUPS=24, T=3 -> NG=4, NW=27648; UB=6
    conv4d_v12<3, 9, 4, 15, 16, 2, 12, 3, 6, 3><<<6912, 256, 0, stream>>>(h1, wf2, b2, h2);
    // conv3: GROUPS=72, T=3 -> NG=3, NW=9984; UB=6
    conv4d_v12<9, 12, 4, 12, 12, 2, 10, 3, 6, 3><<<2496, 256, 0, stream>>>(h2, wf3, b3, h3);
    // conv4: GROUPS=96, T=3 -> NG=2, NW=2048; UB=6
    conv4d_v12<12, 15, 4, 9, 10, 2, 6, 3, 6, 3><<<512, 256, 0, stream>>>(h3, wf4, b4, h4);
    // conv5: GROUPS=90, T=4 -> NG=1, NW=256; UB=6
    conv4d_v12<15, 15, 3, 6, 6, 2, 4, 4, 6, 3><<<64, 256, 0, stream>>>(h4, wf5, b5, h5);

    fc1_mfma<<<28, 256, 0, stream>>>(h5, wfc, fc1b, fc1out);
    fc2_sigmoid<<<1, 256, 0, stream>>>(fc1out, fc2w, fc2b, out);
}

// Round 13
// 905.920 us; speedup vs baseline: 1.1341x; 1.1341x over previous
//
#include <hip/hip_runtime.h>
#include <hip/hip_bf16.h>

// ---------------------------------------------------------------------------
// Model2: 5x 4-D conv (+ReLU) -> FC(3840->100)+ReLU -> FC(100->1)+sigmoid
// v13: v10 structure (rolling-window 1-D d1 tiling, shift-packed 32x32x16
// MFMA, B via global_load_lds dbuf) + ODD-S SHIFT PACKING via a 1-element-
// shifted input copy: conv1 writes h1 and h1s (h1s[i]=h1[i+1]); conv2 lanes
// with odd f16 base offset read h1s at (o-1) (even, 4B-aligned). This lifts
// conv2's N-packing from 9*2=18/32 to 9*3=27/32 cols -> issued MFMA x0.66.
// h3/h4/h5 alias the dead h1s region to stay inside the workspace.
// ---------------------------------------------------------------------------

#define BATCH 256
typedef unsigned int u32;
typedef float    f32x4  __attribute__((ext_vector_type(4)));
typedef float    f32x16 __attribute__((ext_vector_type(16)));
typedef _Float16 f16x8  __attribute__((ext_vector_type(8)));

struct __attribute__((packed, aligned(4))) f16x8w { f16x8 v; };  // 4B-aligned 16B load

// --------------------------- fp32 -> f16 convert ---------------------------
__global__ void cvt_f32_f16(const float* __restrict__ in, _Float16* __restrict__ o, int n8) {
    int i = blockIdx.x * blockDim.x + threadIdx.x;
    if (i >= n8) return;
    const f32x4* p = (const f32x4*)(in + (size_t)i * 8);
    f32x4 a = p[0], b = p[1];
    f16x8 v;
    #pragma unroll
    for (int j = 0; j < 4; ++j) { v[j] = (_Float16)a[j]; v[4 + j] = (_Float16)b[j]; }
    *(f16x8*)(o + (size_t)i * 8) = v;
}

// --------------------------- weight prepack (v5 order) ---------------------
// st = ((ci*KS + k2)*2 + k3p)*KS + k1.  Within a step: k_local = g*8 + j,
// k3 = k3p*2 + g, k4' = j.  col = lane&31 = oc*S + s.
template<int COUT, int CIN, int KS, int S>
__global__ void prepack_v5(const float* __restrict__ w, _Float16* __restrict__ wf) {
    constexpr int STEPS = CIN * KS * 2 * KS;
    constexpr int TOT = STEPS * 512;
    int idx = blockIdx.x * 256 + threadIdx.x;
    if (idx >= TOT) return;
    int j    = idx & 7;
    int lane = (idx >> 3) & 63;
    int st   = idx >> 9;
    int k1 = st % KS;
    int r1 = st / KS;
    int k3p = r1 & 1;
    int r2  = r1 >> 1;
    int k2 = r2 % KS;
    int ci = r2 / KS;
    int gg = lane >> 5, col = lane & 31;
    int oc = col / S, s = col % S;
    int k3 = k3p * 2 + gg;
    int k4 = j - s;
    float v = 0.0f;
    if (oc < COUT && k3 < KS && k4 >= 0 && k4 < KS)
        v = w[((((oc * CIN + ci) * KS + k1) * KS + k2) * KS + k3) * KS + k4];
    wf[idx] = (_Float16)v;
}

// --------------------------- LDS staging helper ----------------------------
template<int BYTES>
__device__ __forceinline__ void stage_b(const _Float16* gsrc, char* ldst, int tid) {
    constexpr int N16 = BYTES / 16;
    const int wv = tid >> 6, ln = tid & 63;
    #pragma unroll
    for (int it = 0; it * 256 < N16; ++it) {
        int u16 = it * 256 + (wv << 6);            // wave-uniform 16B-unit index
        if (u16 < N16) {
            const char* gp = (const char*)gsrc + (size_t)(u16 + ln) * 16;
            __builtin_amdgcn_global_load_lds(
                (const __attribute__((address_space(1))) unsigned int*)gp,
                (__attribute__((address_space(3))) unsigned int*)(ldst + u16 * 16),
                16, 0, 0);
        }
    }
}

// --------------------------- conv kernel (v13) -----------------------------
// SODD: input offsets may be odd -> parity-select between x (even) and
//       xs (x shifted by one f16).   WSHIFT: also write outs[i-1]=v (makes
//       the shifted copy of this layer's output for the next odd-S layer).
template<int CIN, int COUT, int KS, int DIN, int DP, int S, int OP, int T,
         int CG, int MINW, int SODD, int WSHIFT>
__launch_bounds__(256, MINW)
__global__ void conv4d_v13(const _Float16* __restrict__ x,
                           const _Float16* __restrict__ xs,
                           const _Float16* __restrict__ wf,
                           const float* __restrict__ bias,
                           _Float16* __restrict__ out,
                           _Float16* __restrict__ outs) {
    constexpr int DOUT = DIN - KS + 1;
    constexpr int NB   = (DOUT + S - 1) / S;
    constexpr int PCOL = DOUT * DOUT * NB;         // (d2,d3,u) rows per (b,d1)
    constexpr int NTC  = (PCOL + 31) / 32;
    constexpr int NG   = DOUT / T;                 // d1 groups
    static_assert(DOUT % T == 0, "T must divide DOUT");
    constexpr int XD2 = DIN * DP;
    constexpr int XD1 = DIN * XD2;
    constexpr int XCI = DIN * XD1;
    constexpr int GROUPS = CIN * KS * 2;
    static_assert(GROUPS % CG == 0, "CG must divide GROUPS");
    constexpr int CSTEPS = CG * KS;
    constexpr int CBYTES = CSTEPS * 1024;
    constexpr int NCHUNK = GROUPS / CG;
    constexpr int NBUF   = (NCHUNK > 1) ? 2 : 1;
    constexpr int AJ = T + KS - 1;                 // rows touched per group
    constexpr int W  = T + 1;                      // rolling window slots
    constexpr u32 NW   = (u32)BATCH * NG * NTC;
    constexpr u32 POUT = (u32)DOUT * DOUT * DOUT * OP;

    __shared__ char bsm[NBUF * CBYTES];
    const int tid = threadIdx.x;
    u32 wid = blockIdx.x * 4u + (u32)(tid >> 6);
    if (wid >= NW) wid = NW - 1u;
    const int ln = tid & 63;
    const int g  = ln >> 5;
    const int r  = ln & 31;

    u32 tc = wid % (u32)NTC;  u32 q = wid / (u32)NTC;
    u32 d1g = q % (u32)NG;    u32 b = q / (u32)NG;
    u32 rr = tc * 32u + (u32)r;  if (rr >= (u32)PCOL) rr = (u32)PCOL - 1u;
    u32 u  = rr % (u32)NB;    u32 q2 = rr / (u32)NB;
    u32 d3 = q2 % (u32)DOUT;  u32 d2 = q2 / (u32)DOUT;

    // Full f16 offset; parity-select base pointer when S is odd.
    const u32 o = b * (u32)(CIN * XCI) + d1g * (u32)(T * XD1)
                + d2 * (u32)XD2 + d3 * (u32)DP + (u32)(g * DP) + u * (u32)S;
    const char* xb;
    if (SODD) {
        u32 p = o & 1u;
        xb = p ? ((const char*)xs + (size_t)(o - 1u) * 2)
               : ((const char*)x  + (size_t)o * 2);
    } else {
        xb = (const char*)x + (size_t)o * 2;
    }

    f32x16 acc[T];
    #pragma unroll
    for (int t = 0; t < T; ++t)
        #pragma unroll
        for (int i = 0; i < 16; ++i) acc[t][i] = 0.0f;

    stage_b<CBYTES>(wf, &bsm[0], tid);

    #pragma unroll 1
    for (int ch = 0; ch < NCHUNK; ++ch) {
        __syncthreads();   // staging for chunk ch complete (vmcnt drained)
        if (NCHUNK > 1 && ch + 1 < NCHUNK)
            stage_b<CBYTES>(wf + (size_t)(ch + 1) * CSTEPS * 512,
                            &bsm[((ch + 1) & 1) * CBYTES], tid);
        const char* bb = &bsm[(ch & 1) * (NBUF > 1 ? CBYTES : 0)] + ln * 16;
        #pragma unroll
        for (int gi = 0; gi < CG; ++gi) {
            int grp = ch * CG + gi;
            int k3p = grp & 1;
            int k2  = (grp >> 1) % KS;
            int ci  = (grp >> 1) / KS;
            u32 goff = ((u32)ci * (u32)XCI + (u32)k2 * (u32)XD2
                      + (u32)(k3p * 2 * DP)) * 2u;     // even f16 -> even bytes
            const char* ap = xb + goff;

            // Rolling (T+1)-slot window; all indices compile-time constants.
            f16x8 ar[W];
            #pragma unroll
            for (int j = 0; j < T; ++j)
                ar[j] = ((const f16x8w*)(ap + j * (XD1 * 2)))->v;
            #pragma unroll
            for (int k1 = 0; k1 < KS; ++k1) {
                if (T + k1 < AJ)
                    ar[(T + k1) % W] = ((const f16x8w*)(ap + (T + k1) * (XD1 * 2)))->v;
                f16x8 bf = *(const f16x8*)(bb + (gi * KS + k1) * 1024);
                #pragma unroll
                for (int t = 0; t < T; ++t)
                    acc[t] = __builtin_amdgcn_mfma_f32_32x32x16_f16(
                        ar[(k1 + t) % W], bf, acc[t], 0, 0, 0);
            }
        }
    }

    // Epilogue. D: col = lane&31 = oc*S+s, row = (reg&3) + 8*(reg>>2) + 4*g.
    const int oc = r / S, s = r % S;
    if (oc >= COUT) return;
    float bv = bias[oc];
    #pragma unroll
    for (int reg = 0; reg < 16; ++reg) {
        int rowoff = (reg & 3) + 8 * (reg >> 2) + 4 * g;
        u32 rr2 = tc * 32u + (u32)rowoff;
        if (rr2 >= (u32)PCOL) rr2 = (u32)PCOL - 1u;
        u32 uu = rr2 % (u32)NB;  u32 qq = rr2 / (u32)NB;
        u32 dd3 = qq % (u32)DOUT; u32 dd2 = qq / (u32)DOUT;
        u32 d4 = uu * (u32)S + (u32)s;
        if (d4 < (u32)DOUT) {
            u32 obase = (b * (u32)COUT + (u32)oc) * POUT
                      + (dd2 * (u32)DOUT + dd3) * (u32)OP + d4
                      + d1g * (u32)(T * DOUT * DOUT * OP);
            #pragma unroll
            for (int t = 0; t < T; ++t) {
                u32 oidx = obase + (u32)t * (u32)(DOUT * DOUT * OP);
                _Float16 v = (_Float16)fmaxf(acc[t][reg] + bv, 0.0f);
                out[oidx] = v;
                if (WSHIFT) { if (oidx >= 1u) outs[oidx - 1u] = v; }
            }
        }
    }
}

// --------------------------- FC1 (MFMA 16x16x32) ---------------------------
__global__ void prepack_fc1(const float* __restrict__ w, _Float16* __restrict__ wf) {
    int idx = blockIdx.x * 256 + threadIdx.x;        // 7*120*64*8 = 430080
    if (idx >= 430080) return;
    int j    = idx & 7;
    int lane = (idx >> 3) & 63;
    int t9   = idx >> 9;
    int st   = t9 % 120;
    int ni   = t9 / 120;
    int k    = st * 32 + (lane >> 4) * 8 + j;
    int col  = ni * 16 + (lane & 15);
    wf[idx] = (_Float16)((col < 100) ? w[k * 100 + col] : 0.0f);
}

__launch_bounds__(256)
__global__ void fc1_mfma(const _Float16* __restrict__ h,
                         const _Float16* __restrict__ wfc,
                         const float* __restrict__ bias,
                         float* __restrict__ o) {
    int wv   = blockIdx.x * 4 + (threadIdx.x >> 6);   // 0..111
    int lane = threadIdx.x & 63;
    int r = lane & 15, g = lane >> 4;
    int mi = wv / 7, ni = wv % 7;
    const f16x8* A  = (const f16x8*)(h + (size_t)(mi * 16 + r) * 3840);
    const f16x8* Bv = (const f16x8*)wfc;
    f32x4 acc = {0.f, 0.f, 0.f, 0.f};
    #pragma unroll 4
    for (int st = 0; st < 120; ++st) {
        f16x8 a = A[st * 4 + g];
        f16x8 b = Bv[(ni * 120 + st) * 64 + lane];
        acc = __builtin_amdgcn_mfma_f32_16x16x32_f16(a, b, acc, 0, 0, 0);
    }
    int col = ni * 16 + r;
    if (col < 100) {
        float bv = bias[col];
        #pragma unroll
        for (int i = 0; i < 4; ++i) {
            int row = mi * 16 + g * 4 + i;
            o[row * 100 + col] = fmaxf(acc[i] + bv, 0.0f);
        }
    }
}

// --------------------------- FC2 + sigmoid ---------------------------------
__global__ void fc2_sigmoid(const float* __restrict__ h,
                            const float* __restrict__ w,
                            const float* __restrict__ bias,
                            float* __restrict__ out) {
    int b = blockIdx.x * blockDim.x + threadIdx.x;
    if (b >= BATCH) return;
    const float* hb = h + b * 100;
    float acc = bias[0];
    #pragma unroll
    for (int j = 0; j < 100; ++j)
        acc = fmaf(hb[j], w[j], acc);
    out[b] = 1.0f / (1.0f + expf(-acc));
}

// --------------------------- launch ----------------------------------------
extern "C" void kernel_launch(void* const* d_in, const int* in_sizes, int n_in,
                              void* d_out, int out_size, void* d_ws, size_t ws_size,
                              hipStream_t stream) {
    const float* x    = (const float*)d_in[0];
    const float* w1   = (const float*)d_in[1];
    const float* b1   = (const float*)d_in[2];
    const float* w2   = (const float*)d_in[3];
    const float* b2   = (const float*)d_in[4];
    const float* w3   = (const float*)d_in[5];
    const float* b3   = (const float*)d_in[6];
    const float* w4   = (const float*)d_in[7];
    const float* b4   = (const float*)d_in[8];
    const float* w5   = (const float*)d_in[9];
    const float* b5   = (const float*)d_in[10];
    const float* fc1w = (const float*)d_in[11];
    const float* fc1b = (const float*)d_in[12];
    const float* fc2w = (const float*)d_in[13];
    const float* fc2b = (const float*)d_in[14];
    float* out = (float*)d_out;

    // Workspace layout (f16 units). h3/h4/h5 alias h1s (dead after conv2).
    _Float16* W = (_Float16*)d_ws;
    _Float16* x16 = W;                      // 26,873,856  [256,1,18^4]
    _Float16* h1  = W + 26873856;           // 41,472,000  [256,3,15,15,15,16]
    _Float16* h1s = W + 68345856;           // 41,472,000  shifted copy
    _Float16* h2  = W + 109817856;          // 47,775,744  [256,9,12^4]
    _Float16* wf1 = W + 157593600;          //     16,384
    _Float16* wf2 = W + 157609984;          //     49,152
    _Float16* wf3 = W + 157659136;          //    147,456
    _Float16* wf4 = W + 157806592;          //    196,608
    _Float16* wf5 = W + 158003200;          //    138,240
    _Float16* wfc = W + 158141440;          //    430,080
    float* fc1out = (float*)(W + 158571520);//    102,912 B
    _Float16* h3  = h1s;                    // 22,394,880  [256,12,9,9,9,10]
    _Float16* h4  = h1s + 22394880;         //  4,976,640  [256,15,6^4]
    _Float16* h5  = h1s + 27371520;         //    983,040  [256,3840]

    cvt_f32_f16<<<13122, 256, 0, stream>>>(x, x16, 3359232);

    prepack_v5<3, 1, 4, 4><<<64,  256, 0, stream>>>(w1, wf1);
    prepack_v5<9, 3, 4, 3><<<192, 256, 0, stream>>>(w2, wf2);   // S=3 !
    prepack_v5<12, 9, 4, 2><<<576, 256, 0, stream>>>(w3, wf3);
    prepack_v5<15, 12, 4, 2><<<768, 256, 0, stream>>>(w4, wf4);
    prepack_v5<15, 15, 3, 2><<<540, 256, 0, stream>>>(w5, wf5);
    prepack_fc1<<<1680, 256, 0, stream>>>(fc1w, wfc);

    // convs: <CIN,COUT,KS,DIN,DP,S,OP,T,CG,MINW,SODD,WSHIFT>, grid = ceil(NW/4)
    // conv1: T=3, CG=8 (single 32KB chunk); NW=37120; writes h1 + h1s
    conv4d_v13<1, 3, 4, 18, 18, 4, 16, 3, 8, 4, 0, 1>
        <<<9280, 256, 0, stream>>>(x16, x16, wf1, b1, h1, h1s);
    // conv2: S=3 -> 27/32 cols; NB=4, PCOL=576, NTC=18, T=6 -> NW=9216
    conv4d_v13<3, 9, 4, 15, 16, 3, 12, 6, 4, 3, 1, 0>
        <<<2304, 256, 0, stream>>>(h1, h1s, wf2, b2, h2, h2);
    // conv3: T=3 -> NG=3, NTC=13, NW=9984; CG=4
    conv4d_v13<9, 12, 4, 12, 12, 2, 10, 3, 4, 4, 0, 0>
        <<<2496, 256, 0, stream>>>(h2, h2, wf3, b3, h3, h3);
    // conv4: T=3 -> NG=2, NTC=4, NW=2048
    conv4d_v13<12, 15, 4, 9, 10, 2, 6, 3, 4, 4, 0, 0>
        <<<512, 256, 0, stream>>>(h3, h3, wf4, b4, h4, h4);
    // conv5: T=4, CG=6, NW=256
    conv4d_v13<15, 15, 3, 6, 6, 2, 4, 4, 6, 4, 0, 0>
        <<<64, 256, 0, stream>>>(h4, h4, wf5, b5, h5, h5);

    fc1_mfma<<<28, 256, 0, stream>>>(h5, wfc, fc1b, fc1out);
    fc2_sigmoid<<<1, 256, 0, stream>>>(fc1out, fc2w, fc2b, out);
}

// Round 14
// 865.562 us; speedup vs baseline: 1.1870x; 1.0466x over previous
//
#include <hip/hip_runtime.h>
#include <hip/hip_bf16.h>

// ---------------------------------------------------------------------------
// Model2: 5x 4-D conv (+ReLU) -> FC(3840->100)+ReLU -> FC(100->1)+sigmoid
// v14: v13 structure (rolling-window 1-D d1 tiling, shift-packed 32x32x16
// MFMA, B via global_load_lds dbuf, odd-S via shifted input copy) plus:
//  - conv1 S=4->5 (col-fill 12/32 -> 15/32, MFMA x0.76) using x16s shifted
//    copy written by the cvt kernel
//  - all 6 weight prepacks fused into one launch
//  - s_setprio(1) around each pure-MFMA t-burst (T5)
// Workspace aliasing: h2 overlays dead x16/x16s; h3/h4/h5 overlay dead h1s.
// ---------------------------------------------------------------------------

#define BATCH 256
typedef unsigned int u32;
typedef float    f32x4  __attribute__((ext_vector_type(4)));
typedef float    f32x16 __attribute__((ext_vector_type(16)));
typedef _Float16 f16x8  __attribute__((ext_vector_type(8)));

struct __attribute__((packed, aligned(4))) f16x8w { f16x8 v; };  // 4B-aligned 16B load

// ------------------- fp32 -> f16 convert (plain + shifted) -----------------
__global__ void cvt_f32_f16_pair(const float* __restrict__ in,
                                 _Float16* __restrict__ o,
                                 _Float16* __restrict__ os, int n8) {
    int i = blockIdx.x * blockDim.x + threadIdx.x;
    if (i >= n8) return;
    const f32x4* p = (const f32x4*)(in + (size_t)i * 8);
    f32x4 a = p[0], b = p[1];
    float c = (i + 1 < n8) ? in[(size_t)i * 8 + 8] : 0.0f;
    f16x8 v, vs;
    #pragma unroll
    for (int j = 0; j < 4; ++j) { v[j] = (_Float16)a[j]; v[4 + j] = (_Float16)b[j]; }
    #pragma unroll
    for (int j = 0; j < 7; ++j) vs[j] = v[j + 1];
    vs[7] = (_Float16)c;
    *(f16x8*)(o  + (size_t)i * 8) = v;
    *(f16x8*)(os + (size_t)i * 8) = vs;   // os[p] = o[p+1]
}

// --------------------------- fused weight prepack --------------------------
// Same element math as v5 prepack: st = ((ci*KS + k2)*2 + k3p)*KS + k1;
// k3 = k3p*2 + (lane>>5), k4' = j; col = lane&31 = oc*S + s.
__device__ __forceinline__ _Float16 conv_wf_elem(const float* __restrict__ w,
        int e, int COUT, int CIN, int KS, int S) {
    int j    = e & 7;
    int lane = (e >> 3) & 63;
    int st   = e >> 9;
    int k1 = st % KS;
    int r1 = st / KS;
    int k3p = r1 & 1;
    int r2  = r1 >> 1;
    int k2 = r2 % KS;
    int ci = r2 / KS;
    int gg = lane >> 5, col = lane & 31;
    int oc = col / S, s = col % S;
    int k3 = k3p * 2 + gg;
    int k4 = j - s;
    float v = 0.0f;
    if (oc < COUT && k3 < KS && k4 >= 0 && k4 < KS)
        v = w[((((oc * CIN + ci) * KS + k1) * KS + k2) * KS + k3) * KS + k4];
    return (_Float16)v;
}

__global__ void prepack_all(const float* __restrict__ w1, const float* __restrict__ w2,
                            const float* __restrict__ w3, const float* __restrict__ w4,
                            const float* __restrict__ w5, const float* __restrict__ fw,
                            _Float16* __restrict__ wf1, _Float16* __restrict__ wf2,
                            _Float16* __restrict__ wf3, _Float16* __restrict__ wf4,
                            _Float16* __restrict__ wf5, _Float16* __restrict__ wfc) {
    int idx = blockIdx.x * 256 + threadIdx.x;
    if (idx < 16384)  { wf1[idx] = conv_wf_elem(w1, idx, 3, 1, 4, 5);  return; }
    idx -= 16384;
    if (idx < 49152)  { wf2[idx] = conv_wf_elem(w2, idx, 9, 3, 4, 3);  return; }
    idx -= 49152;
    if (idx < 147456) { wf3[idx] = conv_wf_elem(w3, idx, 12, 9, 4, 2); return; }
    idx -= 147456;
    if (idx < 196608) { wf4[idx] = conv_wf_elem(w4, idx, 15, 12, 4, 2); return; }
    idx -= 196608;
    if (idx < 138240) { wf5[idx] = conv_wf_elem(w5, idx, 15, 15, 3, 2); return; }
    idx -= 138240;
    if (idx < 430080) {
        int j    = idx & 7;
        int lane = (idx >> 3) & 63;
        int t9   = idx >> 9;
        int st   = t9 % 120;
        int ni   = t9 / 120;
        int k    = st * 32 + (lane >> 4) * 8 + j;
        int col  = ni * 16 + (lane & 15);
        wfc[idx] = (_Float16)((col < 100) ? fw[k * 100 + col] : 0.0f);
    }
}

// --------------------------- LDS staging helper ----------------------------
template<int BYTES>
__device__ __forceinline__ void stage_b(const _Float16* gsrc, char* ldst, int tid) {
    constexpr int N16 = BYTES / 16;
    const int wv = tid >> 6, ln = tid & 63;
    #pragma unroll
    for (int it = 0; it * 256 < N16; ++it) {
        int u16 = it * 256 + (wv << 6);            // wave-uniform 16B-unit index
        if (u16 < N16) {
            const char* gp = (const char*)gsrc + (size_t)(u16 + ln) * 16;
            __builtin_amdgcn_global_load_lds(
                (const __attribute__((address_space(1))) unsigned int*)gp,
                (__attribute__((address_space(3))) unsigned int*)(ldst + u16 * 16),
                16, 0, 0);
        }
    }
}

// --------------------------- conv kernel (v14) -----------------------------
template<int CIN, int COUT, int KS, int DIN, int DP, int S, int OP, int T,
         int CG, int MINW, int SODD, int WSHIFT>
__launch_bounds__(256, MINW)
__global__ void conv4d_v14(const _Float16* __restrict__ x,
                           const _Float16* __restrict__ xs,
                           const _Float16* __restrict__ wf,
                           const float* __restrict__ bias,
                           _Float16* __restrict__ out,
                           _Float16* __restrict__ outs) {
    constexpr int DOUT = DIN - KS + 1;
    constexpr int NB   = (DOUT + S - 1) / S;
    constexpr int PCOL = DOUT * DOUT * NB;         // (d2,d3,u) rows per (b,d1)
    constexpr int NTC  = (PCOL + 31) / 32;
    constexpr int NG   = DOUT / T;                 // d1 groups
    static_assert(DOUT % T == 0, "T must divide DOUT");
    constexpr int XD2 = DIN * DP;
    constexpr int XD1 = DIN * XD2;
    constexpr int XCI = DIN * XD1;
    constexpr int GROUPS = CIN * KS * 2;
    static_assert(GROUPS % CG == 0, "CG must divide GROUPS");
    constexpr int CSTEPS = CG * KS;
    constexpr int CBYTES = CSTEPS * 1024;
    constexpr int NCHUNK = GROUPS / CG;
    constexpr int NBUF   = (NCHUNK > 1) ? 2 : 1;
    constexpr int AJ = T + KS - 1;                 // rows touched per group
    constexpr int W  = T + 1;                      // rolling window slots
    constexpr u32 NW   = (u32)BATCH * NG * NTC;
    constexpr u32 POUT = (u32)DOUT * DOUT * DOUT * OP;

    __shared__ char bsm[NBUF * CBYTES];
    const int tid = threadIdx.x;
    u32 wid = blockIdx.x * 4u + (u32)(tid >> 6);
    if (wid >= NW) wid = NW - 1u;
    const int ln = tid & 63;
    const int g  = ln >> 5;
    const int r  = ln & 31;

    u32 tc = wid % (u32)NTC;  u32 q = wid / (u32)NTC;
    u32 d1g = q % (u32)NG;    u32 b = q / (u32)NG;
    u32 rr = tc * 32u + (u32)r;  if (rr >= (u32)PCOL) rr = (u32)PCOL - 1u;
    u32 u  = rr % (u32)NB;    u32 q2 = rr / (u32)NB;
    u32 d3 = q2 % (u32)DOUT;  u32 d2 = q2 / (u32)DOUT;

    // Full f16 offset; parity-select base pointer when S is odd.
    const u32 o = b * (u32)(CIN * XCI) + d1g * (u32)(T * XD1)
                + d2 * (u32)XD2 + d3 * (u32)DP + (u32)(g * DP) + u * (u32)S;
    const char* xb;
    if (SODD) {
        u32 p = o & 1u;
        xb = p ? ((const char*)xs + (size_t)(o - 1u) * 2)
               : ((const char*)x  + (size_t)o * 2);
    } else {
        xb = (const char*)x + (size_t)o * 2;
    }

    f32x16 acc[T];
    #pragma unroll
    for (int t = 0; t < T; ++t)
        #pragma unroll
        for (int i = 0; i < 16; ++i) acc[t][i] = 0.0f;

    stage_b<CBYTES>(wf, &bsm[0], tid);

    #pragma unroll 1
    for (int ch = 0; ch < NCHUNK; ++ch) {
        __syncthreads();   // staging for chunk ch complete (vmcnt drained)
        if (NCHUNK > 1 && ch + 1 < NCHUNK)
            stage_b<CBYTES>(wf + (size_t)(ch + 1) * CSTEPS * 512,
                            &bsm[((ch + 1) & 1) * CBYTES], tid);
        const char* bb = &bsm[(ch & 1) * (NBUF > 1 ? CBYTES : 0)] + ln * 16;
        #pragma unroll
        for (int gi = 0; gi < CG; ++gi) {
            int grp = ch * CG + gi;
            int k3p = grp & 1;
            int k2  = (grp >> 1) % KS;
            int ci  = (grp >> 1) / KS;
            u32 goff = ((u32)ci * (u32)XCI + (u32)k2 * (u32)XD2
                      + (u32)(k3p * 2 * DP)) * 2u;     // even f16 -> even bytes
            const char* ap = xb + goff;

            // Rolling (T+1)-slot window; all indices compile-time constants.
            f16x8 ar[W];
            #pragma unroll
            for (int j = 0; j < T; ++j)
                ar[j] = ((const f16x8w*)(ap + j * (XD1 * 2)))->v;
            #pragma unroll
            for (int k1 = 0; k1 < KS; ++k1) {
                if (T + k1 < AJ)
                    ar[(T + k1) % W] = ((const f16x8w*)(ap + (T + k1) * (XD1 * 2)))->v;
                f16x8 bf = *(const f16x8*)(bb + (gi * KS + k1) * 1024);
                __builtin_amdgcn_s_setprio(1);
                #pragma unroll
                for (int t = 0; t < T; ++t)
                    acc[t] = __builtin_amdgcn_mfma_f32_32x32x16_f16(
                        ar[(k1 + t) % W], bf, acc[t], 0, 0, 0);
                __builtin_amdgcn_s_setprio(0);
            }
        }
    }

    // Epilogue. D: col = lane&31 = oc*S+s, row = (reg&3) + 8*(reg>>2) + 4*g.
    const int oc = r / S, s = r % S;
    if (oc >= COUT) return;
    float bv = bias[oc];
    #pragma unroll
    for (int reg = 0; reg < 16; ++reg) {
        int rowoff = (reg & 3) + 8 * (reg >> 2) + 4 * g;
        u32 rr2 = tc * 32u + (u32)rowoff;
        if (rr2 >= (u32)PCOL) rr2 = (u32)PCOL - 1u;
        u32 uu = rr2 % (u32)NB;  u32 qq = rr2 / (u32)NB;
        u32 dd3 = qq % (u32)DOUT; u32 dd2 = qq / (u32)DOUT;
        u32 d4 = uu * (u32)S + (u32)s;
        if (d4 < (u32)DOUT) {
            u32 obase = (b * (u32)COUT + (u32)oc) * POUT
                      + (dd2 * (u32)DOUT + dd3) * (u32)OP + d4
                      + d1g * (u32)(T * DOUT * DOUT * OP);
            #pragma unroll
            for (int t = 0; t < T; ++t) {
                u32 oidx = obase + (u32)t * (u32)(DOUT * DOUT * OP);
                _Float16 v = (_Float16)fmaxf(acc[t][reg] + bv, 0.0f);
                out[oidx] = v;
                if (WSHIFT) { if (oidx >= 1u) outs[oidx - 1u] = v; }
            }
        }
    }
}

// --------------------------- FC1 (MFMA 16x16x32) ---------------------------
__launch_bounds__(256)
__global__ void fc1_mfma(const _Float16* __restrict__ h,
                         const _Float16* __restrict__ wfc,
                         const float* __restrict__ bias,
                         float* __restrict__ o) {
    int wv   = blockIdx.x * 4 + (threadIdx.x >> 6);   // 0..111
    int lane = threadIdx.x & 63;
    int r = lane & 15, g = lane >> 4;
    int mi = wv / 7, ni = wv % 7;
    const f16x8* A  = (const f16x8*)(h + (size_t)(mi * 16 + r) * 3840);
    const f16x8* Bv = (const f16x8*)wfc;
    f32x4 acc = {0.f, 0.f, 0.f, 0.f};
    #pragma unroll 4
    for (int st = 0; st < 120; ++st) {
        f16x8 a = A[st * 4 + g];
        f16x8 b = Bv[(ni * 120 + st) * 64 + lane];
        acc = __builtin_amdgcn_mfma_f32_16x16x32_f16(a, b, acc, 0, 0, 0);
    }
    int col = ni * 16 + r;
    if (col < 100) {
        float bv = bias[col];
        #pragma unroll
        for (int i = 0; i < 4; ++i) {
            int row = mi * 16 + g * 4 + i;
            o[row * 100 + col] = fmaxf(acc[i] + bv, 0.0f);
        }
    }
}

// --------------------------- FC2 + sigmoid ---------------------------------
__global__ void fc2_sigmoid(const float* __restrict__ h,
                            const float* __restrict__ w,
                            const float* __restrict__ bias,
                            float* __restrict__ out) {
    int b = blockIdx.x * blockDim.x + threadIdx.x;
    if (b >= BATCH) return;
    const float* hb = h + b * 100;
    float acc = bias[0];
    #pragma unroll
    for (int j = 0; j < 100; ++j)
        acc = fmaf(hb[j], w[j], acc);
    out[b] = 1.0f / (1.0f + expf(-acc));
}

// --------------------------- launch ----------------------------------------
extern "C" void kernel_launch(void* const* d_in, const int* in_sizes, int n_in,
                              void* d_out, int out_size, void* d_ws, size_t ws_size,
                              hipStream_t stream) {
    const float* x    = (const float*)d_in[0];
    const float* w1   = (const float*)d_in[1];
    const float* b1   = (const float*)d_in[2];
    const float* w2   = (const float*)d_in[3];
    const float* b2   = (const float*)d_in[4];
    const float* w3   = (const float*)d_in[5];
    const float* b3   = (const float*)d_in[6];
    const float* w4   = (const float*)d_in[7];
    const float* b4   = (const float*)d_in[8];
    const float* w5   = (const float*)d_in[9];
    const float* b5   = (const float*)d_in[10];
    const float* fc1w = (const float*)d_in[11];
    const float* fc1b = (const float*)d_in[12];
    const float* fc2w = (const float*)d_in[13];
    const float* fc2b = (const float*)d_in[14];
    float* out = (float*)d_out;

    // Workspace layout (f16 units), lifetime-aliased:
    //   [x16 26.87M][x16s 26.87M][h1 41.47M][h1s 41.47M][wf/fc tail ~1.1M]
    //   h2 (47.78M) overlays x16+x16s (dead after conv1);
    //   h3/h4/h5 (28.35M) overlay h1s (dead after conv2).  Total ~275 MB.
    _Float16* W = (_Float16*)d_ws;
    _Float16* x16  = W;                       // 26,873,856
    _Float16* x16s = W + 26873856;            // 26,873,856 (ends 53,747,712)
    _Float16* h1   = W + 53747712;            // 41,472,000 (ends 95,219,712)
    _Float16* h1s  = W + 95219712;            // 41,472,000 (ends 136,691,712)
    _Float16* h2   = W;                       // 47,775,744 (overlay, ends 47.78M)
    _Float16* h3   = h1s;                     // 22,394,880
    _Float16* h4   = h1s + 22394880;          //  4,976,640
    _Float16* h5   = h1s + 27371520;          //    983,040
    _Float16* wf1  = W + 136691712;           //     16,384
    _Float16* wf2  = W + 136708096;           //     49,152
    _Float16* wf3  = W + 136757248;           //    147,456
    _Float16* wf4  = W + 136904704;           //    196,608
    _Float16* wf5  = W + 137101312;           //    138,240
    _Float16* wfc  = W + 137239552;           //    430,080
    float* fc1out  = (float*)(W + 137669632); //     51,456 f32

    // x -> f16 (plain + 1-element-shifted copy for conv1's odd S)
    cvt_f32_f16_pair<<<13122, 256, 0, stream>>>(x, x16, x16s, 3359232);
    // all weight prepacks in one launch (977,920 elements)
    prepack_all<<<3820, 256, 0, stream>>>(w1, w2, w3, w4, w5, fc1w,
                                          wf1, wf2, wf3, wf4, wf5, wfc);

    // convs: <CIN,COUT,KS,DIN,DP,S,OP,T,CG,MINW,SODD,WSHIFT>, grid = ceil(NW/4)
    // conv1: S=5 (odd) -> NB=3, PCOL=675, NTC=22, T=3 -> NG=5, NW=28160
    conv4d_v14<1, 3, 4, 18, 18, 5, 16, 3, 8, 4, 1, 1>
        <<<7040, 256, 0, stream>>>(x16, x16s, wf1, b1, h1, h1s);
    // conv2: S=3 -> NB=4, PCOL=576, NTC=18, T=6 -> NG=2, NW=9216
    conv4d_v14<3, 9, 4, 15, 16, 3, 12, 6, 4, 3, 1, 0>
        <<<2304, 256, 0, stream>>>(h1, h1s, wf2, b2, h2, h2);
    // conv3: S=2 -> NB=5, PCOL=405, NTC=13, T=3 -> NG=3, NW=9984
    conv4d_v14<9, 12, 4, 12, 12, 2, 10, 3, 4, 4, 0, 0>
        <<<2496, 256, 0, stream>>>(h2, h2, wf3, b3, h3, h3);
    // conv4: T=3 -> NG=2, NTC=4, NW=2048
    conv4d_v14<12, 15, 4, 9, 10, 2, 6, 3, 4, 4, 0, 0>
        <<<512, 256, 0, stream>>>(h3, h3, wf4, b4, h4, h4);
    // conv5: T=4, CG=6, NW=256
    conv4d_v14<15, 15, 3, 6, 6, 2, 4, 4, 6, 4, 0, 0>
        <<<64, 256, 0, stream>>>(h4, h4, wf5, b5, h5, h5);

    fc1_mfma<<<28, 256, 0, stream>>>(h5, wfc, fc1b, fc1out);
    fc2_sigmoid<<<1, 256, 0, stream>>>(fc1out, fc2w, fc2b, out);
}